// Round 6
// baseline (404.681 us; speedup 1.0000x reference)
//
#include <hip/hip_runtime.h>
#include <hip/hip_fp16.h>

#define N_IND 1000000
#define N_ORG 300000
#define N_EXT 100000
#define F 64
#define E_PER 1000000
#define NREL 14

#define BW 1024                 // bucket width (nodes)
#define NB_IND 977              // ceil(N_IND/BW)
#define NB_ORG 293              // ceil(N_ORG/BW)
#define NBKT 1270               // used buckets
#define NBKT_PAD 1280           // padded (5 per thread at 256 thr)
#define CHUNK 8192              // edges per column
#define COLS_PER_REL 123        // ceil(E_PER/CHUNK)
#define NCOL (NREL * COLS_PER_REL) // 1722
#define LAST_N (E_PER - (COLS_PER_REL - 1) * CHUNK) // 576 (divisible by 4)
#define NBLK_SCAT 512

#define FIX_SCALE 262144.0f            // 2^18
#define FIX_INV   3.814697265625e-6f   // 2^-18

// ---- workspace layout (in 4-byte words) ----
static const size_t OFF_PAY      = 0;          // u32[NCOL][CHUNK] = 14,106,624
static const size_t OFF_CNTOFF   = 14106624;   // u32[NCOL][NBKT_PAD] = 2,204,160
static const size_t OFF_CNTOFF_T = 16310784;   // u32[NBKT_PAD][NCOL] = 2,204,160
static const size_t OFF_P_IND    = 18514944;   // fp16[5][N_IND]  = 2,500,000 words
static const size_t OFF_P_ORG    = 21014944;   // fp16[5][N_ORG]  =   750,000
static const size_t OFF_P_EXT    = 21764944;   // fp16[4][N_EXT]  =   200,000
static const size_t OFF_BASE_IND = 21964944;   // f32[N_IND]
static const size_t OFF_BASE_ORG = 22964944;   // f32[N_ORG]
static const size_t OFF_WM_IND   = 23264944;   // 6*64
static const size_t OFF_WM_ORG   = 23265328;   // 6*64
static const size_t OFF_WM_EXT   = 23265712;   // 4*64
static const size_t OFF_BSUM     = 23265968;   // 2
// total 23,265,970 words = 93.1 MB

__global__ void prep_kernel(const float* __restrict__ Wl,
                            const float* __restrict__ Wr,
                            const float* __restrict__ b,
                            float* __restrict__ wm_ind,
                            float* __restrict__ wm_org,
                            float* __restrict__ wm_ext,
                            float* __restrict__ bsum) {
    int t = threadIdx.x; // 64 threads
    const int ind_wl[5] = {0, 3, 6, 7, 10};
    const int org_wl[5] = {1, 4, 8, 11, 13};
    const int ext_wl[4] = {2, 5, 9, 12};
    const int ind_r[7]  = {0, 1, 2, 7, 8, 9, 13};
    const int org_r[7]  = {3, 4, 5, 6, 10, 11, 12};
#pragma unroll
    for (int k = 0; k < 5; ++k) wm_ind[k * 64 + t] = Wl[ind_wl[k] * 64 + t];
#pragma unroll
    for (int k = 0; k < 5; ++k) wm_org[k * 64 + t] = Wl[org_wl[k] * 64 + t];
#pragma unroll
    for (int k = 0; k < 4; ++k) wm_ext[k * 64 + t] = Wl[ext_wl[k] * 64 + t];
    float si = 0.f, so = 0.f;
#pragma unroll
    for (int k = 0; k < 7; ++k) {
        si += Wr[ind_r[k] * 64 + t];
        so += Wr[org_r[k] * 64 + t];
    }
    wm_ind[5 * 64 + t] = si;
    wm_org[5 * 64 + t] = so;
    if (t == 0) {
        float bi = 0.f, bo = 0.f;
#pragma unroll
        for (int k = 0; k < 7; ++k) { bi += b[ind_r[k]]; bo += b[org_r[k]]; }
        bsum[0] = bi;
        bsum[1] = bo;
    }
}

// Rank-1 projections -> fp16 p slices (+ f32 base for dst types).
template <int K, bool HASBASE>
__global__ __launch_bounds__(256) void proj_kernel(
    const float* __restrict__ x, int n,
    const float* __restrict__ wm,
    __half* __restrict__ p,           // [K or K-1][n] fp16
    float* __restrict__ base_out,
    const float* __restrict__ bsum) {
    int i = blockIdx.x * 256 + threadIdx.x;
    if (i >= n) return;
    const float4* xv = (const float4*)(x + (size_t)i * F);
    float acc[K];
#pragma unroll
    for (int k = 0; k < K; ++k) acc[k] = 0.f;
#pragma unroll
    for (int c = 0; c < 16; ++c) {
        float4 v = xv[c];
#pragma unroll
        for (int k = 0; k < K; ++k) {
            const float* w = wm + k * 64 + c * 4;
            acc[k] += v.x * w[0] + v.y * w[1] + v.z * w[2] + v.w * w[3];
        }
    }
    constexpr int NP = HASBASE ? K - 1 : K;
#pragma unroll
    for (int k = 0; k < NP; ++k) p[(size_t)k * n + i] = __float2half_rn(acc[k]);
    if (HASBASE) base_out[i] = acc[K - 1] + bsum[0];
}

// Persistent scatter v2: no LDS staging. Per column: int4 LDS histogram ->
// shfl wave scan -> direct sorted global writes (32 KB window per column,
// L2 write-combines to full lines). LDS ~10.3 KB -> 7-8 blocks/CU.
__global__ __launch_bounds__(256) void scatter_kernel(
    const int* __restrict__ ei,
    const unsigned short* __restrict__ p_ind,
    const unsigned short* __restrict__ p_org,
    const unsigned short* __restrict__ p_ext,
    unsigned* __restrict__ pay,      // [NCOL][CHUNK]
    unsigned* __restrict__ cntoff) { // [NCOL][NBKT_PAD]
    const int srcType[NREL] = {0,1,2,0,1,2,0,0,1,2,0,1,2,1};
    const int srcSlot[NREL] = {0,0,0,1,1,1,2,3,2,2,4,3,3,4};
    const int dstType[NREL] = {0,0,0,1,1,1,1,0,0,0,1,1,1,0};
    const int dstSlot[NREL] = {0,1,2,0,1,2,3,3,4,5,4,5,6,6};

    __shared__ unsigned h[NBKT_PAD];
    __shared__ unsigned cur[NBKT_PAD];
    __shared__ unsigned wsum[4];

    const int t = threadIdx.x;
    const int lane = t & 63, wv = t >> 6;

    for (int cid = blockIdx.x; cid < NCOL; cid += NBLK_SCAT) {
        const int r = cid / COLS_PER_REL;
        const int i = cid - r * COLS_PER_REL;
        const int n = (i == COLS_PER_REL - 1) ? LAST_N : CHUNK;
        const int* srcp = ei + ((size_t)r * 2 + 0) * E_PER + (size_t)i * CHUNK;
        const int* dstp = ei + ((size_t)r * 2 + 1) * E_PER + (size_t)i * CHUNK;
        const int boff = dstType[r] ? NB_IND : 0;
        const unsigned slotbits = (unsigned)dstSlot[r] << 10;
        const int st = srcType[r];
        const unsigned short* psrc =
            (st == 0) ? p_ind + (size_t)srcSlot[r] * N_IND :
            (st == 1) ? p_org + (size_t)srcSlot[r] * N_ORG :
                        p_ext + (size_t)srcSlot[r] * N_EXT;

        // pass 1: histogram (int4 loads)
#pragma unroll
        for (int j = 0; j < 5; ++j) h[t * 5 + j] = 0u;
        __syncthreads();
        const int4* dst4 = (const int4*)dstp;
        const int n4 = n >> 2;
        for (int k = t; k < n4; k += 256) {
            int4 d = dst4[k];
            atomicAdd(&h[boff + (d.x >> 10)], 1u);
            atomicAdd(&h[boff + (d.y >> 10)], 1u);
            atomicAdd(&h[boff + (d.z >> 10)], 1u);
            atomicAdd(&h[boff + (d.w >> 10)], 1u);
        }
        __syncthreads();

        // exclusive scan over 1280 counters: 5/thread + shfl wave scan
        unsigned loc[5], s0 = 0;
#pragma unroll
        for (int j = 0; j < 5; ++j) { loc[j] = h[t * 5 + j]; s0 += loc[j]; }
        unsigned x = s0;
#pragma unroll
        for (int d = 1; d < 64; d <<= 1) {
            unsigned v = __shfl_up(x, d, 64);
            if (lane >= d) x += v;
        }
        if (lane == 63) wsum[wv] = x;
        __syncthreads();
        unsigned base = x - s0;
        for (int j = 0; j < wv; ++j) base += wsum[j];
        unsigned* co = cntoff + (size_t)cid * NBKT_PAD;
#pragma unroll
        for (int j = 0; j < 5; ++j) {
            co[t * 5 + j] = (base << 16) | loc[j];
            cur[t * 5 + j] = base;
            base += loc[j];
        }
        __syncthreads();

        // pass 2: gather p, write payload word directly at sorted position
        const int4* src4 = (const int4*)srcp;
        unsigned* payc = pay + (size_t)cid * CHUNK;
        for (int k = t; k < n4; k += 256) {
            int4 s = src4[k];
            int4 d = dst4[k];
#pragma unroll
            for (int q = 0; q < 4; ++q) {
                int src = (q == 0) ? s.x : (q == 1) ? s.y : (q == 2) ? s.z : s.w;
                int dst = (q == 0) ? d.x : (q == 1) ? d.y : (q == 2) ? d.z : d.w;
                unsigned pvbits = psrc[src];
                unsigned word = (pvbits << 16) | slotbits | (unsigned)(dst & (BW - 1));
                unsigned pos = atomicAdd(&cur[boff + (dst >> 10)], 1u);
                payc[pos] = word;
            }
        }
        __syncthreads();
    }
}

// Transpose cntoff [NCOL][NBKT_PAD] -> [NBKT_PAD][NCOL] (32x32 tiles).
__global__ __launch_bounds__(256) void transpose_kernel(
    const unsigned* __restrict__ in, unsigned* __restrict__ out) {
    __shared__ unsigned tb[32][33];
    const int c0 = blockIdx.x * 32; // col in 'in' (bucket)
    const int r0 = blockIdx.y * 32; // row in 'in' (cid)
    const int tx = threadIdx.x & 31, ty = threadIdx.x >> 5; // ty 0..7
#pragma unroll
    for (int j = 0; j < 32; j += 8) {
        int r = r0 + ty + j, c = c0 + tx;
        if (r < NCOL && c < NBKT_PAD) tb[ty + j][tx] = in[(size_t)r * NBKT_PAD + c];
    }
    __syncthreads();
#pragma unroll
    for (int j = 0; j < 32; j += 8) {
        int r = c0 + ty + j, c = r0 + tx;
        if (r < NBKT_PAD && c < NCOL) out[(size_t)r * NCOL + c] = tb[tx][ty + j];
    }
}

// One block per bucket: walk all columns' (off,cnt), read dense payload
// segments, packed fixed-point LDS accumulate, fused finalize + sigmoid.
__global__ __launch_bounds__(256) void gather_kernel(
    const unsigned* __restrict__ pay,
    const unsigned* __restrict__ cntoffT,
    const float* __restrict__ base_ind,
    const float* __restrict__ base_org,
    float* __restrict__ out) {
    __shared__ unsigned acc[7 * BW];
    const int blk = blockIdx.x; // 0..NBKT-1 (ind: 0..976, org: 977..1269)
    const int t = threadIdx.x;
    for (int j = t; j < 7 * BW; j += 256) acc[j] = 0u;
    __syncthreads();

    const unsigned* row = cntoffT + (size_t)blk * NCOL;
    for (int cid = t; cid < NCOL; cid += 256) {
        unsigned co = row[cid];
        unsigned cnt = co & 0xffffu;
        if (!cnt) continue;
        const unsigned* seg = pay + (size_t)cid * CHUNK + (co >> 16);
        for (unsigned e = 0; e < cnt; ++e) {
            unsigned w = seg[e];
            unsigned short hs = (unsigned short)(w >> 16);
            __half hh;
            __builtin_memcpy(&hh, &hs, 2);
            float pv = __half2float(hh);
            int fixed = (int)rintf(pv * FIX_SCALE);
            unsigned contrib = (1u << 26) + (unsigned)fixed;
            atomicAdd(&acc[((w >> 10) & 7u) * BW + (w & (BW - 1))], contrib);
        }
    }
    __syncthreads();

    const bool isInd = blk < NB_IND;
    const int b = isInd ? blk : blk - NB_IND;
    const int nn = isInd ? N_IND : N_ORG;
    const float* basep = isInd ? base_ind : base_org;
    float* outp = isInd ? out : out + N_IND;
    for (int loc = t; loc < BW; loc += 256) {
        int g = b * BW + loc;
        if (g < nn) {
            float a = basep[g];
#pragma unroll
            for (int k = 0; k < 7; ++k) {
                unsigned w = acc[k * BW + loc];
                int s26 = ((int)(w << 6)) >> 6;         // sign-extend low 26
                unsigned c = (w - (unsigned)s26) >> 26; // exact count
                a += (float)s26 * FIX_INV / fmaxf((float)c, 1.0f);
            }
            outp[g] = 1.0f / (1.0f + __expf(-a));
        }
    }
}

extern "C" void kernel_launch(void* const* d_in, const int* in_sizes, int n_in,
                              void* d_out, int out_size, void* d_ws, size_t ws_size,
                              hipStream_t stream) {
    const float* x_ind = (const float*)d_in[0];
    const float* x_org = (const float*)d_in[1];
    const float* x_ext = (const float*)d_in[2];
    const float* Wl    = (const float*)d_in[3];
    const float* Wr    = (const float*)d_in[4];
    const float* b     = (const float*)d_in[5];
    const int*   ei    = (const int*)d_in[6];
    float* out = (float*)d_out;

    float* ws = (float*)d_ws;
    unsigned* pay      = (unsigned*)(ws + OFF_PAY);
    unsigned* cntoff   = (unsigned*)(ws + OFF_CNTOFF);
    unsigned* cntoffT  = (unsigned*)(ws + OFF_CNTOFF_T);
    __half* p_ind      = (__half*)(ws + OFF_P_IND);
    __half* p_org      = (__half*)(ws + OFF_P_ORG);
    __half* p_ext      = (__half*)(ws + OFF_P_EXT);
    float* base_ind    = ws + OFF_BASE_IND;
    float* base_org    = ws + OFF_BASE_ORG;
    float* wm_ind      = ws + OFF_WM_IND;
    float* wm_org      = ws + OFF_WM_ORG;
    float* wm_ext      = ws + OFF_WM_EXT;
    float* bsum        = ws + OFF_BSUM;

    prep_kernel<<<1, 64, 0, stream>>>(Wl, Wr, b, wm_ind, wm_org, wm_ext, bsum);

    proj_kernel<6, true><<<(N_IND + 255) / 256, 256, 0, stream>>>(
        x_ind, N_IND, wm_ind, p_ind, base_ind, bsum + 0);
    proj_kernel<6, true><<<(N_ORG + 255) / 256, 256, 0, stream>>>(
        x_org, N_ORG, wm_org, p_org, base_org, bsum + 1);
    proj_kernel<4, false><<<(N_EXT + 255) / 256, 256, 0, stream>>>(
        x_ext, N_EXT, wm_ext, p_ext, nullptr, bsum);

    scatter_kernel<<<NBLK_SCAT, 256, 0, stream>>>(
        ei, (const unsigned short*)p_ind, (const unsigned short*)p_org,
        (const unsigned short*)p_ext, pay, cntoff);

    dim3 tgrid((NBKT_PAD + 31) / 32, (NCOL + 31) / 32);
    transpose_kernel<<<tgrid, 256, 0, stream>>>(cntoff, cntoffT);

    gather_kernel<<<NBKT, 256, 0, stream>>>(pay, cntoffT, base_ind, base_org, out);
}

// Round 7
// 302.251 us; speedup vs baseline: 1.3389x; 1.3389x over previous
//
#include <hip/hip_runtime.h>
#include <hip/hip_fp16.h>

#define N_IND 1000000
#define N_ORG 300000
#define N_EXT 100000
#define F 64
#define E_PER 1000000
#define NREL 14

#define BW 1024                 // bucket width (nodes)
#define NB_IND 977              // ceil(N_IND/BW)
#define NB_ORG 293              // ceil(N_ORG/BW)
#define NBKT 1270               // used buckets
#define NBKT_PAD 1280           // padded (5 per thread at 256 thr)
#define CHUNK 8192              // edges per column
#define COLS_PER_REL 123        // ceil(E_PER/CHUNK)
#define NCOL (NREL * COLS_PER_REL) // 1722
#define LAST_N (E_PER - (COLS_PER_REL - 1) * CHUNK) // 576 (divisible by 4)

#define FIX_SCALE 262144.0f            // 2^18
#define FIX_INV   3.814697265625e-6f   // 2^-18

// ---- workspace layout (in 4-byte words) ----
static const size_t OFF_PAY      = 0;          // u32[NCOL][CHUNK] = 14,106,624
static const size_t OFF_CNTOFF   = 14106624;   // u32[NCOL][NBKT_PAD] = 2,204,160
static const size_t OFF_CNTOFF_T = 16310784;   // u32[NBKT_PAD][NCOL] = 2,204,160
static const size_t OFF_P_IND    = 18514944;   // fp16[5][N_IND]  = 2,500,000 words
static const size_t OFF_P_ORG    = 21014944;   // fp16[5][N_ORG]  =   750,000
static const size_t OFF_P_EXT    = 21764944;   // fp16[4][N_EXT]  =   200,000
static const size_t OFF_BASE_IND = 21964944;   // f32[N_IND]
static const size_t OFF_BASE_ORG = 22964944;   // f32[N_ORG]
static const size_t OFF_WM_IND   = 23264944;   // 6*64
static const size_t OFF_WM_ORG   = 23265328;   // 6*64
static const size_t OFF_WM_EXT   = 23265712;   // 4*64
static const size_t OFF_BSUM     = 23265968;   // 2
// total 23,265,970 words = 93.1 MB

__global__ void prep_kernel(const float* __restrict__ Wl,
                            const float* __restrict__ Wr,
                            const float* __restrict__ b,
                            float* __restrict__ wm_ind,
                            float* __restrict__ wm_org,
                            float* __restrict__ wm_ext,
                            float* __restrict__ bsum) {
    int t = threadIdx.x; // 64 threads
    const int ind_wl[5] = {0, 3, 6, 7, 10};
    const int org_wl[5] = {1, 4, 8, 11, 13};
    const int ext_wl[4] = {2, 5, 9, 12};
    const int ind_r[7]  = {0, 1, 2, 7, 8, 9, 13};
    const int org_r[7]  = {3, 4, 5, 6, 10, 11, 12};
#pragma unroll
    for (int k = 0; k < 5; ++k) wm_ind[k * 64 + t] = Wl[ind_wl[k] * 64 + t];
#pragma unroll
    for (int k = 0; k < 5; ++k) wm_org[k * 64 + t] = Wl[org_wl[k] * 64 + t];
#pragma unroll
    for (int k = 0; k < 4; ++k) wm_ext[k * 64 + t] = Wl[ext_wl[k] * 64 + t];
    float si = 0.f, so = 0.f;
#pragma unroll
    for (int k = 0; k < 7; ++k) {
        si += Wr[ind_r[k] * 64 + t];
        so += Wr[org_r[k] * 64 + t];
    }
    wm_ind[5 * 64 + t] = si;
    wm_org[5 * 64 + t] = so;
    if (t == 0) {
        float bi = 0.f, bo = 0.f;
#pragma unroll
        for (int k = 0; k < 7; ++k) { bi += b[ind_r[k]]; bo += b[org_r[k]]; }
        bsum[0] = bi;
        bsum[1] = bo;
    }
}

// Rank-1 projections -> fp16 p slices (+ f32 base for dst types).
template <int K, bool HASBASE>
__global__ __launch_bounds__(256) void proj_kernel(
    const float* __restrict__ x, int n,
    const float* __restrict__ wm,
    __half* __restrict__ p,           // [K or K-1][n] fp16
    float* __restrict__ base_out,
    const float* __restrict__ bsum) {
    int i = blockIdx.x * 256 + threadIdx.x;
    if (i >= n) return;
    const float4* xv = (const float4*)(x + (size_t)i * F);
    float acc[K];
#pragma unroll
    for (int k = 0; k < K; ++k) acc[k] = 0.f;
#pragma unroll
    for (int c = 0; c < 16; ++c) {
        float4 v = xv[c];
#pragma unroll
        for (int k = 0; k < K; ++k) {
            const float* w = wm + k * 64 + c * 4;
            acc[k] += v.x * w[0] + v.y * w[1] + v.z * w[2] + v.w * w[3];
        }
    }
    constexpr int NP = HASBASE ? K - 1 : K;
#pragma unroll
    for (int k = 0; k < NP; ++k) p[(size_t)k * n + i] = __float2half_rn(acc[k]);
    if (HASBASE) base_out[i] = acc[K - 1] + bsum[0];
}

// Scatter v3: one column per block (grid=NCOL), LDS-staged sort (dense
// stream-out -> write-combine friendly), merged hist/cursor array + shfl
// scan -> 37.3 KB LDS -> 4 blocks/CU.
__global__ __launch_bounds__(256) void scatter_kernel(
    const int* __restrict__ ei,
    const unsigned short* __restrict__ p_ind,
    const unsigned short* __restrict__ p_org,
    const unsigned short* __restrict__ p_ext,
    unsigned* __restrict__ pay,      // [NCOL][CHUNK]
    unsigned* __restrict__ cntoff) { // [NCOL][NBKT_PAD]
    const int srcType[NREL] = {0,1,2,0,1,2,0,0,1,2,0,1,2,1};
    const int srcSlot[NREL] = {0,0,0,1,1,1,2,3,2,2,4,3,3,4};
    const int dstType[NREL] = {0,0,0,1,1,1,1,0,0,0,1,1,1,0};
    const int dstSlot[NREL] = {0,1,2,0,1,2,3,3,4,5,4,5,6,6};

    __shared__ unsigned h[NBKT_PAD];     // histogram, then cursor (reused)
    __shared__ unsigned stage[CHUNK];
    __shared__ unsigned wsum[4];

    const int t = threadIdx.x;
    const int lane = t & 63, wv = t >> 6;

    const int cid = blockIdx.x;
    const int r = cid / COLS_PER_REL;
    const int i = cid - r * COLS_PER_REL;
    const int n = (i == COLS_PER_REL - 1) ? LAST_N : CHUNK;
    const int* srcp = ei + ((size_t)r * 2 + 0) * E_PER + (size_t)i * CHUNK;
    const int* dstp = ei + ((size_t)r * 2 + 1) * E_PER + (size_t)i * CHUNK;
    const int boff = dstType[r] ? NB_IND : 0;
    const unsigned slotbits = (unsigned)dstSlot[r] << 10;
    const int st = srcType[r];
    const unsigned short* psrc =
        (st == 0) ? p_ind + (size_t)srcSlot[r] * N_IND :
        (st == 1) ? p_org + (size_t)srcSlot[r] * N_ORG :
                    p_ext + (size_t)srcSlot[r] * N_EXT;

    // pass 1: histogram (int4 loads)
#pragma unroll
    for (int j = 0; j < 5; ++j) h[t * 5 + j] = 0u;
    __syncthreads();
    const int4* dst4 = (const int4*)dstp;
    const int n4 = n >> 2;
    for (int k = t; k < n4; k += 256) {
        int4 d = dst4[k];
        atomicAdd(&h[boff + (d.x >> 10)], 1u);
        atomicAdd(&h[boff + (d.y >> 10)], 1u);
        atomicAdd(&h[boff + (d.z >> 10)], 1u);
        atomicAdd(&h[boff + (d.w >> 10)], 1u);
    }
    __syncthreads();

    // exclusive scan over 1280 counters: 5/thread + shfl wave scan.
    // Each thread reads ONLY its own 5 slots -> safe to overwrite them with
    // cursor bases afterwards (h reused as cursor array).
    unsigned loc[5], s0 = 0;
#pragma unroll
    for (int j = 0; j < 5; ++j) { loc[j] = h[t * 5 + j]; s0 += loc[j]; }
    unsigned x = s0;
#pragma unroll
    for (int d = 1; d < 64; d <<= 1) {
        unsigned v = __shfl_up(x, d, 64);
        if (lane >= d) x += v;
    }
    if (lane == 63) wsum[wv] = x;
    __syncthreads();
    unsigned base = x - s0;
    for (int j = 0; j < wv; ++j) base += wsum[j];
    unsigned* co = cntoff + (size_t)cid * NBKT_PAD;
#pragma unroll
    for (int j = 0; j < 5; ++j) {
        co[t * 5 + j] = (base << 16) | loc[j];
        h[t * 5 + j] = base;   // cursor seed (own slot only)
        base += loc[j];
    }
    __syncthreads();

    // pass 2: gather p, place into LDS stage at sorted positions
    const int4* src4 = (const int4*)srcp;
    for (int k = t; k < n4; k += 256) {
        int4 s = src4[k];
        int4 d = dst4[k];
#pragma unroll
        for (int q = 0; q < 4; ++q) {
            int src = (q == 0) ? s.x : (q == 1) ? s.y : (q == 2) ? s.z : s.w;
            int dst = (q == 0) ? d.x : (q == 1) ? d.y : (q == 2) ? d.z : d.w;
            unsigned pvbits = psrc[src];
            unsigned word = (pvbits << 16) | slotbits | (unsigned)(dst & (BW - 1));
            unsigned pos = atomicAdd(&h[boff + (dst >> 10)], 1u);
            stage[pos] = word;
        }
    }
    __syncthreads();

    // dense stream-out (full 128B lines -> write-combines cleanly)
    unsigned* payc = pay + (size_t)cid * CHUNK;
    for (int k = t; k < n; k += 256) payc[k] = stage[k];
}

// Transpose cntoff [NCOL][NBKT_PAD] -> [NBKT_PAD][NCOL] (32x32 tiles).
__global__ __launch_bounds__(256) void transpose_kernel(
    const unsigned* __restrict__ in, unsigned* __restrict__ out) {
    __shared__ unsigned tb[32][33];
    const int c0 = blockIdx.x * 32; // col in 'in' (bucket)
    const int r0 = blockIdx.y * 32; // row in 'in' (cid)
    const int tx = threadIdx.x & 31, ty = threadIdx.x >> 5; // ty 0..7
#pragma unroll
    for (int j = 0; j < 32; j += 8) {
        int r = r0 + ty + j, c = c0 + tx;
        if (r < NCOL && c < NBKT_PAD) tb[ty + j][tx] = in[(size_t)r * NBKT_PAD + c];
    }
    __syncthreads();
#pragma unroll
    for (int j = 0; j < 32; j += 8) {
        int r = c0 + ty + j, c = r0 + tx;
        if (r < NBKT_PAD && c < NCOL) out[(size_t)r * NCOL + c] = tb[tx][ty + j];
    }
}

// One block per bucket: walk all columns' (off,cnt), read dense payload
// segments, packed fixed-point LDS accumulate, fused finalize + sigmoid.
__global__ __launch_bounds__(256) void gather_kernel(
    const unsigned* __restrict__ pay,
    const unsigned* __restrict__ cntoffT,
    const float* __restrict__ base_ind,
    const float* __restrict__ base_org,
    float* __restrict__ out) {
    __shared__ unsigned acc[7 * BW];
    const int blk = blockIdx.x; // 0..NBKT-1 (ind: 0..976, org: 977..1269)
    const int t = threadIdx.x;
    for (int j = t; j < 7 * BW; j += 256) acc[j] = 0u;
    __syncthreads();

    const unsigned* row = cntoffT + (size_t)blk * NCOL;
    for (int cid = t; cid < NCOL; cid += 256) {
        unsigned co = row[cid];
        unsigned cnt = co & 0xffffu;
        if (!cnt) continue;
        const unsigned* seg = pay + (size_t)cid * CHUNK + (co >> 16);
        for (unsigned e = 0; e < cnt; ++e) {
            unsigned w = seg[e];
            unsigned short hs = (unsigned short)(w >> 16);
            __half hh;
            __builtin_memcpy(&hh, &hs, 2);
            float pv = __half2float(hh);
            int fixed = (int)rintf(pv * FIX_SCALE);
            unsigned contrib = (1u << 26) + (unsigned)fixed;
            atomicAdd(&acc[((w >> 10) & 7u) * BW + (w & (BW - 1))], contrib);
        }
    }
    __syncthreads();

    const bool isInd = blk < NB_IND;
    const int b = isInd ? blk : blk - NB_IND;
    const int nn = isInd ? N_IND : N_ORG;
    const float* basep = isInd ? base_ind : base_org;
    float* outp = isInd ? out : out + N_IND;
    for (int loc = t; loc < BW; loc += 256) {
        int g = b * BW + loc;
        if (g < nn) {
            float a = basep[g];
#pragma unroll
            for (int k = 0; k < 7; ++k) {
                unsigned w = acc[k * BW + loc];
                int s26 = ((int)(w << 6)) >> 6;         // sign-extend low 26
                unsigned c = (w - (unsigned)s26) >> 26; // exact count
                a += (float)s26 * FIX_INV / fmaxf((float)c, 1.0f);
            }
            outp[g] = 1.0f / (1.0f + __expf(-a));
        }
    }
}

extern "C" void kernel_launch(void* const* d_in, const int* in_sizes, int n_in,
                              void* d_out, int out_size, void* d_ws, size_t ws_size,
                              hipStream_t stream) {
    const float* x_ind = (const float*)d_in[0];
    const float* x_org = (const float*)d_in[1];
    const float* x_ext = (const float*)d_in[2];
    const float* Wl    = (const float*)d_in[3];
    const float* Wr    = (const float*)d_in[4];
    const float* b     = (const float*)d_in[5];
    const int*   ei    = (const int*)d_in[6];
    float* out = (float*)d_out;

    float* ws = (float*)d_ws;
    unsigned* pay      = (unsigned*)(ws + OFF_PAY);
    unsigned* cntoff   = (unsigned*)(ws + OFF_CNTOFF);
    unsigned* cntoffT  = (unsigned*)(ws + OFF_CNTOFF_T);
    __half* p_ind      = (__half*)(ws + OFF_P_IND);
    __half* p_org      = (__half*)(ws + OFF_P_ORG);
    __half* p_ext      = (__half*)(ws + OFF_P_EXT);
    float* base_ind    = ws + OFF_BASE_IND;
    float* base_org    = ws + OFF_BASE_ORG;
    float* wm_ind      = ws + OFF_WM_IND;
    float* wm_org      = ws + OFF_WM_ORG;
    float* wm_ext      = ws + OFF_WM_EXT;
    float* bsum        = ws + OFF_BSUM;

    prep_kernel<<<1, 64, 0, stream>>>(Wl, Wr, b, wm_ind, wm_org, wm_ext, bsum);

    proj_kernel<6, true><<<(N_IND + 255) / 256, 256, 0, stream>>>(
        x_ind, N_IND, wm_ind, p_ind, base_ind, bsum + 0);
    proj_kernel<6, true><<<(N_ORG + 255) / 256, 256, 0, stream>>>(
        x_org, N_ORG, wm_org, p_org, base_org, bsum + 1);
    proj_kernel<4, false><<<(N_EXT + 255) / 256, 256, 0, stream>>>(
        x_ext, N_EXT, wm_ext, p_ext, nullptr, bsum);

    scatter_kernel<<<NCOL, 256, 0, stream>>>(
        ei, (const unsigned short*)p_ind, (const unsigned short*)p_org,
        (const unsigned short*)p_ext, pay, cntoff);

    dim3 tgrid((NBKT_PAD + 31) / 32, (NCOL + 31) / 32);
    transpose_kernel<<<tgrid, 256, 0, stream>>>(cntoff, cntoffT);

    gather_kernel<<<NBKT, 256, 0, stream>>>(pay, cntoffT, base_ind, base_org, out);
}

// Round 8
// 288.474 us; speedup vs baseline: 1.4028x; 1.0478x over previous
//
#include <hip/hip_runtime.h>
#include <hip/hip_fp16.h>

#define N_IND 1000000
#define N_ORG 300000
#define N_EXT 100000
#define F 64
#define E_PER 1000000
#define NREL 14

#define BW 1024                 // bucket width (nodes)
#define NB_IND 977              // ceil(N_IND/BW), within-type buckets
#define NB_ORG 293              // ceil(N_ORG/BW)
#define NBKT 1270               // gather grid (ind then org)
#define NB_H 1024               // per-column histogram size (covers 977), 4/thread
#define CHUNK 4096              // edges per column
#define COLS_PER_REL 245        // ceil(E_PER/CHUNK)
#define NCOL (NREL * COLS_PER_REL) // 3430
#define LAST_N (E_PER - (COLS_PER_REL - 1) * CHUNK) // 576 (divisible by 4)
#define COLS_PER_TYPE (7 * COLS_PER_REL) // 1715

#define FIX_SCALE 262144.0f            // 2^18
#define FIX_INV   3.814697265625e-6f   // 2^-18

// ---- workspace layout (in 4-byte words) ----
static const size_t OFF_PAY      = 0;          // u32[NCOL][CHUNK] = 14,049,280
static const size_t OFF_CNTOFF   = 14049280;   // u32[NCOL][NB_H] = 3,512,320
static const size_t OFF_CNTOFF_T = 17561600;   // u32[NB_H][NCOL] = 3,512,320
static const size_t OFF_P_IND    = 21073920;   // fp16[5][N_IND]  = 2,500,000 words
static const size_t OFF_P_ORG    = 23573920;   // fp16[5][N_ORG]  =   750,000
static const size_t OFF_P_EXT    = 24323920;   // fp16[4][N_EXT]  =   200,000
static const size_t OFF_BASE_IND = 24523920;   // f32[N_IND]
static const size_t OFF_BASE_ORG = 25523920;   // f32[N_ORG]
static const size_t OFF_WM_IND   = 25823920;   // 6*64
static const size_t OFF_WM_ORG   = 25824304;   // 6*64
static const size_t OFF_WM_EXT   = 25824688;   // 4*64
static const size_t OFF_BSUM     = 25824944;   // 2
// total 25,824,946 words = 103.3 MB (ws >= 105.6 MB proven in round 1)

__global__ void prep_kernel(const float* __restrict__ Wl,
                            const float* __restrict__ Wr,
                            const float* __restrict__ b,
                            float* __restrict__ wm_ind,
                            float* __restrict__ wm_org,
                            float* __restrict__ wm_ext,
                            float* __restrict__ bsum) {
    int t = threadIdx.x; // 64 threads
    const int ind_wl[5] = {0, 3, 6, 7, 10};
    const int org_wl[5] = {1, 4, 8, 11, 13};
    const int ext_wl[4] = {2, 5, 9, 12};
    const int ind_r[7]  = {0, 1, 2, 7, 8, 9, 13};
    const int org_r[7]  = {3, 4, 5, 6, 10, 11, 12};
#pragma unroll
    for (int k = 0; k < 5; ++k) wm_ind[k * 64 + t] = Wl[ind_wl[k] * 64 + t];
#pragma unroll
    for (int k = 0; k < 5; ++k) wm_org[k * 64 + t] = Wl[org_wl[k] * 64 + t];
#pragma unroll
    for (int k = 0; k < 4; ++k) wm_ext[k * 64 + t] = Wl[ext_wl[k] * 64 + t];
    float si = 0.f, so = 0.f;
#pragma unroll
    for (int k = 0; k < 7; ++k) {
        si += Wr[ind_r[k] * 64 + t];
        so += Wr[org_r[k] * 64 + t];
    }
    wm_ind[5 * 64 + t] = si;
    wm_org[5 * 64 + t] = so;
    if (t == 0) {
        float bi = 0.f, bo = 0.f;
#pragma unroll
        for (int k = 0; k < 7; ++k) { bi += b[ind_r[k]]; bo += b[org_r[k]]; }
        bsum[0] = bi;
        bsum[1] = bo;
    }
}

// Rank-1 projections -> fp16 p slices (+ f32 base for dst types).
template <int K, bool HASBASE>
__global__ __launch_bounds__(256) void proj_kernel(
    const float* __restrict__ x, int n,
    const float* __restrict__ wm,
    __half* __restrict__ p,           // [K or K-1][n] fp16
    float* __restrict__ base_out,
    const float* __restrict__ bsum) {
    int i = blockIdx.x * 256 + threadIdx.x;
    if (i >= n) return;
    const float4* xv = (const float4*)(x + (size_t)i * F);
    float acc[K];
#pragma unroll
    for (int k = 0; k < K; ++k) acc[k] = 0.f;
#pragma unroll
    for (int c = 0; c < 16; ++c) {
        float4 v = xv[c];
#pragma unroll
        for (int k = 0; k < K; ++k) {
            const float* w = wm + k * 64 + c * 4;
            acc[k] += v.x * w[0] + v.y * w[1] + v.z * w[2] + v.w * w[3];
        }
    }
    constexpr int NP = HASBASE ? K - 1 : K;
#pragma unroll
    for (int k = 0; k < NP; ++k) p[(size_t)k * n + i] = __float2half_rn(acc[k]);
    if (HASBASE) base_out[i] = acc[K - 1] + bsum[0];
}

// Scatter v4: CHUNK=4096, per-type histogram (1024 entries), dst kept in
// VGPRs across passes. LDS = 16K stage + 4K hist ~= 20.5 KB -> 7 blocks/CU.
__global__ __launch_bounds__(256, 7) void scatter_kernel(
    const int* __restrict__ ei,
    const unsigned short* __restrict__ p_ind,
    const unsigned short* __restrict__ p_org,
    const unsigned short* __restrict__ p_ext,
    unsigned* __restrict__ pay,      // [NCOL][CHUNK]
    unsigned* __restrict__ cntoff) { // [NCOL][NB_H]
    const int srcType[NREL] = {0,1,2,0,1,2,0,0,1,2,0,1,2,1};
    const int srcSlot[NREL] = {0,0,0,1,1,1,2,3,2,2,4,3,3,4};
    const int dstSlot[NREL] = {0,1,2,0,1,2,3,3,4,5,4,5,6,6};

    __shared__ unsigned h[NB_H];     // histogram, then cursor (reused)
    __shared__ unsigned stage[CHUNK];
    __shared__ unsigned wsum[4];

    const int t = threadIdx.x;
    const int lane = t & 63, wv = t >> 6;

    const int cid = blockIdx.x;
    const int r = cid / COLS_PER_REL;
    const int i = cid - r * COLS_PER_REL;
    const int n = (i == COLS_PER_REL - 1) ? LAST_N : CHUNK;
    const int n4 = n >> 2;
    const int* srcp = ei + ((size_t)r * 2 + 0) * E_PER + (size_t)i * CHUNK;
    const int* dstp = ei + ((size_t)r * 2 + 1) * E_PER + (size_t)i * CHUNK;
    const unsigned slotbits = (unsigned)dstSlot[r] << 10;
    const int st = srcType[r];
    const unsigned short* psrc =
        (st == 0) ? p_ind + (size_t)srcSlot[r] * N_IND :
        (st == 1) ? p_org + (size_t)srcSlot[r] * N_ORG :
                    p_ext + (size_t)srcSlot[r] * N_EXT;

    // pass 1: histogram; keep dst values in registers for pass 2
#pragma unroll
    for (int j = 0; j < 4; ++j) h[t * 4 + j] = 0u;
    __syncthreads();
    const int4* dst4 = (const int4*)dstp;
    int4 dreg[4];
#pragma unroll
    for (int u = 0; u < 4; ++u) {
        int k = t + u * 256;
        if (k < n4) {
            int4 d = dst4[k];
            dreg[u] = d;
            atomicAdd(&h[d.x >> 10], 1u);
            atomicAdd(&h[d.y >> 10], 1u);
            atomicAdd(&h[d.z >> 10], 1u);
            atomicAdd(&h[d.w >> 10], 1u);
        }
    }
    __syncthreads();

    // exclusive scan over 1024 counters: 4/thread + shfl wave scan.
    // Each thread reads only its own 4 slots -> safe to overwrite after the
    // wsum barrier (h reused as cursor array).
    unsigned loc[4], s0 = 0;
#pragma unroll
    for (int j = 0; j < 4; ++j) { loc[j] = h[t * 4 + j]; s0 += loc[j]; }
    unsigned x = s0;
#pragma unroll
    for (int d = 1; d < 64; d <<= 1) {
        unsigned v = __shfl_up(x, d, 64);
        if (lane >= d) x += v;
    }
    if (lane == 63) wsum[wv] = x;
    __syncthreads();
    unsigned base = x - s0;
    for (int j = 0; j < wv; ++j) base += wsum[j];
    unsigned* co = cntoff + (size_t)cid * NB_H;
#pragma unroll
    for (int j = 0; j < 4; ++j) {
        co[t * 4 + j] = (base << 16) | loc[j];
        h[t * 4 + j] = base;   // cursor seed (own slot only)
        base += loc[j];
    }
    __syncthreads();

    // pass 2: gather p, place into LDS stage at sorted positions
    const int4* src4 = (const int4*)srcp;
#pragma unroll
    for (int u = 0; u < 4; ++u) {
        int k = t + u * 256;
        if (k < n4) {
            int4 s = src4[k];
            int4 d = dreg[u];
#pragma unroll
            for (int q = 0; q < 4; ++q) {
                int src = (q == 0) ? s.x : (q == 1) ? s.y : (q == 2) ? s.z : s.w;
                int dst = (q == 0) ? d.x : (q == 1) ? d.y : (q == 2) ? d.z : d.w;
                unsigned pvbits = psrc[src];
                unsigned word = (pvbits << 16) | slotbits | (unsigned)(dst & (BW - 1));
                unsigned pos = atomicAdd(&h[dst >> 10], 1u);
                stage[pos] = word;
            }
        }
    }
    __syncthreads();

    // dense stream-out (full lines -> write-combine friendly)
    unsigned* payc = pay + (size_t)cid * CHUNK;
    for (int k = t; k < n; k += 256) payc[k] = stage[k];
}

// Transpose cntoff [NCOL][NB_H] -> [NB_H][NCOL] (32x32 tiles).
__global__ __launch_bounds__(256) void transpose_kernel(
    const unsigned* __restrict__ in, unsigned* __restrict__ out) {
    __shared__ unsigned tb[32][33];
    const int c0 = blockIdx.x * 32; // col in 'in' (bucket)
    const int r0 = blockIdx.y * 32; // row in 'in' (cid)
    const int tx = threadIdx.x & 31, ty = threadIdx.x >> 5; // ty 0..7
#pragma unroll
    for (int j = 0; j < 32; j += 8) {
        int r = r0 + ty + j, c = c0 + tx;
        if (r < NCOL && c < NB_H) tb[ty + j][tx] = in[(size_t)r * NB_H + c];
    }
    __syncthreads();
#pragma unroll
    for (int j = 0; j < 32; j += 8) {
        int r = c0 + ty + j, c = r0 + tx;
        if (r < NB_H && c < NCOL) out[(size_t)r * NCOL + c] = tb[tx][ty + j];
    }
}

// One block per (type, bucket): walk the 1715 columns of this dst type,
// read dense payload segments, packed fixed-point LDS accumulate, fused
// finalize + sigmoid.
__global__ __launch_bounds__(256) void gather_kernel(
    const unsigned* __restrict__ pay,
    const unsigned* __restrict__ cntoffT,
    const float* __restrict__ base_ind,
    const float* __restrict__ base_org,
    float* __restrict__ out) {
    __shared__ unsigned acc[7 * BW];
    const int blk = blockIdx.x; // 0..976 ind, 977..1269 org
    const int t = threadIdx.x;
    for (int j = t; j < 7 * BW; j += 256) acc[j] = 0u;
    __syncthreads();

    const bool isInd = blk < NB_IND;
    const int b = isInd ? blk : blk - NB_IND; // within-type bucket
    const int relsI[7] = {0, 1, 2, 7, 8, 9, 13};
    const int relsO[7] = {3, 4, 5, 6, 10, 11, 12};

    const unsigned* row = cntoffT + (size_t)b * NCOL;
    for (int j = t; j < COLS_PER_TYPE; j += 256) {
        int rl = j / COLS_PER_REL;
        int c = j - rl * COLS_PER_REL;
        int rel = isInd ? relsI[rl] : relsO[rl];
        int cid = rel * COLS_PER_REL + c;
        unsigned co = row[cid];
        unsigned cnt = co & 0xffffu;
        if (!cnt) continue;
        const unsigned* seg = pay + (size_t)cid * CHUNK + (co >> 16);
        for (unsigned e = 0; e < cnt; ++e) {
            unsigned w = seg[e];
            unsigned short hs = (unsigned short)(w >> 16);
            __half hh;
            __builtin_memcpy(&hh, &hs, 2);
            float pv = __half2float(hh);
            int fixed = (int)rintf(pv * FIX_SCALE);
            unsigned contrib = (1u << 26) + (unsigned)fixed;
            atomicAdd(&acc[((w >> 10) & 7u) * BW + (w & (BW - 1))], contrib);
        }
    }
    __syncthreads();

    const int nn = isInd ? N_IND : N_ORG;
    const float* basep = isInd ? base_ind : base_org;
    float* outp = isInd ? out : out + N_IND;
    for (int loc = t; loc < BW; loc += 256) {
        int g = b * BW + loc;
        if (g < nn) {
            float a = basep[g];
#pragma unroll
            for (int k = 0; k < 7; ++k) {
                unsigned w = acc[k * BW + loc];
                int s26 = ((int)(w << 6)) >> 6;         // sign-extend low 26
                unsigned c = (w - (unsigned)s26) >> 26; // exact count
                a += (float)s26 * FIX_INV / fmaxf((float)c, 1.0f);
            }
            outp[g] = 1.0f / (1.0f + __expf(-a));
        }
    }
}

extern "C" void kernel_launch(void* const* d_in, const int* in_sizes, int n_in,
                              void* d_out, int out_size, void* d_ws, size_t ws_size,
                              hipStream_t stream) {
    const float* x_ind = (const float*)d_in[0];
    const float* x_org = (const float*)d_in[1];
    const float* x_ext = (const float*)d_in[2];
    const float* Wl    = (const float*)d_in[3];
    const float* Wr    = (const float*)d_in[4];
    const float* b     = (const float*)d_in[5];
    const int*   ei    = (const int*)d_in[6];
    float* out = (float*)d_out;

    float* ws = (float*)d_ws;
    unsigned* pay      = (unsigned*)(ws + OFF_PAY);
    unsigned* cntoff   = (unsigned*)(ws + OFF_CNTOFF);
    unsigned* cntoffT  = (unsigned*)(ws + OFF_CNTOFF_T);
    __half* p_ind      = (__half*)(ws + OFF_P_IND);
    __half* p_org      = (__half*)(ws + OFF_P_ORG);
    __half* p_ext      = (__half*)(ws + OFF_P_EXT);
    float* base_ind    = ws + OFF_BASE_IND;
    float* base_org    = ws + OFF_BASE_ORG;
    float* wm_ind      = ws + OFF_WM_IND;
    float* wm_org      = ws + OFF_WM_ORG;
    float* wm_ext      = ws + OFF_WM_EXT;
    float* bsum        = ws + OFF_BSUM;

    prep_kernel<<<1, 64, 0, stream>>>(Wl, Wr, b, wm_ind, wm_org, wm_ext, bsum);

    proj_kernel<6, true><<<(N_IND + 255) / 256, 256, 0, stream>>>(
        x_ind, N_IND, wm_ind, p_ind, base_ind, bsum + 0);
    proj_kernel<6, true><<<(N_ORG + 255) / 256, 256, 0, stream>>>(
        x_org, N_ORG, wm_org, p_org, base_org, bsum + 1);
    proj_kernel<4, false><<<(N_EXT + 255) / 256, 256, 0, stream>>>(
        x_ext, N_EXT, wm_ext, p_ext, nullptr, bsum);

    scatter_kernel<<<NCOL, 256, 0, stream>>>(
        ei, (const unsigned short*)p_ind, (const unsigned short*)p_org,
        (const unsigned short*)p_ext, pay, cntoff);

    dim3 tgrid((NB_H + 31) / 32, (NCOL + 31) / 32);
    transpose_kernel<<<tgrid, 256, 0, stream>>>(cntoff, cntoffT);

    gather_kernel<<<NBKT, 256, 0, stream>>>(pay, cntoffT, base_ind, base_org, out);
}